// Round 1
// 283.732 us; speedup vs baseline: 1.0115x; 1.0115x over previous
//
#include <hip/hip_runtime.h>
#include <hip/hip_bf16.h>

// ChebConv K=4. out[b,v,o] = bias[o] + sum_{c<256} xs[c&3][v,(c>>2)*2+b] * Wflat[c*64+o]
// R11: replace atomic random-scatter CSR build (52MB HBM write amplification,
// ~60us) with two-pass bucketed scatter:
//   bin1_k: LDS-staged binning by row>>9 into 98 buckets, coalesced burst flush.
//   bin2_k: one block per bucket -> row_fill atomics + epack stores stay in one
//           XCD's L2; each epack line written back once.
// Bucket bases in tmp reuse padded row_ptr (row_ptr[b<<9]) -> no extra scans.
// spmm / final_k unchanged from R10.

#define NV 50000
#define NE 800000
#define XROW 128       // elements per x row = 2 batches * 64 features
#define NROWS 100000
#define NTILES 6250    // NROWS / 16
#define SCAN_NBLK 196
#define EPMAX 1600000  // >= NE + 15*NV (padded CSR upper bound)
#define NB 98          // row buckets of 512 rows: ceil(NV/512)
#define BSHIFT 9
#define CHUNK 4096     // edges per bin1 block
#define P1_BLOCKS 196  // ceil(NE / CHUNK)

using u16 = unsigned short;
using u32 = unsigned int;
using u64 = unsigned long long;
typedef __bf16 bf16x8 __attribute__((ext_vector_type(8)));
typedef float f32x4 __attribute__((ext_vector_type(4)));

__device__ __forceinline__ float bflo(u32 g) { return __uint_as_float(g << 16); }
__device__ __forceinline__ float bfhi(u32 g) { return __uint_as_float(g & 0xffff0000u); }
__device__ __forceinline__ u32 pack_bf2(float a, float b) {
    u16 ha = __builtin_bit_cast(u16, (__bf16)a);
    u16 hb = __builtin_bit_cast(u16, (__bf16)b);
    return (u32)ha | ((u32)hb << 16);
}
__device__ __forceinline__ float unpack_f16hi(u32 rec) {
    u16 h = (u16)(rec >> 16);
    return (float)__builtin_bit_cast(_Float16, h);
}
__device__ __forceinline__ int pad16(int n) { return (n + 15) & ~15; }

__global__ void hist_k(const int* __restrict__ rows, int* __restrict__ cnt) {
    int i = blockIdx.x * blockDim.x + threadIdx.x;
    if (i < NE) atomicAdd(&cnt[rows[i]], 1);
}

__global__ __launch_bounds__(256) void scan1_k(const int* __restrict__ cnt, int* __restrict__ bsum) {
    __shared__ int s[256];
    int t = threadIdx.x;
    int i = blockIdx.x * 256 + t;
    s[t] = (i < NV) ? pad16(cnt[i]) : 0;
    __syncthreads();
    for (int off = 128; off > 0; off >>= 1) {
        if (t < off) s[t] += s[t + off];
        __syncthreads();
    }
    if (t == 0) bsum[blockIdx.x] = s[0];
}

__global__ __launch_bounds__(256) void scan2_k(int* __restrict__ bsum) {
    __shared__ int s[256];
    int t = threadIdx.x;
    s[t] = (t < SCAN_NBLK) ? bsum[t] : 0;
    __syncthreads();
    for (int off = 1; off < 256; off <<= 1) {
        int v = (t >= off) ? s[t - off] : 0;
        __syncthreads();
        s[t] += v;
        __syncthreads();
    }
    if (t < SCAN_NBLK) bsum[t] = (t == 0) ? 0 : s[t - 1];
}

__global__ __launch_bounds__(256) void scan3_k(const int* __restrict__ cnt, const int* __restrict__ bsum,
                                               int* __restrict__ row_ptr, int* __restrict__ row_fill,
                                               int* __restrict__ bfill) {
    __shared__ int s[256];
    int t = threadIdx.x;
    int i = blockIdx.x * 256 + t;
    int myv = (i < NV) ? pad16(cnt[i]) : 0;
    s[t] = myv;
    __syncthreads();
    for (int off = 1; off < 256; off <<= 1) {
        int v = (t >= off) ? s[t - off] : 0;
        __syncthreads();
        s[t] += v;
        __syncthreads();
    }
    if (i < NV) {
        int p = bsum[blockIdx.x] + s[t] - myv;
        row_ptr[i] = p;
        row_fill[i] = p;
        if ((i & ((1 << BSHIFT) - 1)) == 0) bfill[i >> BSHIFT] = p;  // bucket base in tmp
        if (i == NV - 1) row_ptr[NV] = p + myv;
    }
}

// Pass 1: bin edges by row>>BSHIFT into tmp (u64 rec: row<<32 | col | f16(val)<<16).
// LDS-staged so each bucket run flushes as a contiguous coalesced burst.
__global__ __launch_bounds__(256) void bin1_k(const int* __restrict__ rows, const int* __restrict__ cols,
                                              const float* __restrict__ vals,
                                              int* __restrict__ bfill, u64* __restrict__ tmp) {
    __shared__ int bcnt[NB];
    __shared__ int bofs[NB];
    __shared__ int bcur[NB];
    __shared__ int gbase[NB];
    __shared__ int sc[128];
    __shared__ u64 stage[CHUNK];  // 32 KB
    int t = threadIdx.x;
    int base = blockIdx.x * CHUNK;
    int n = NE - base;
    if (n > CHUNK) n = CHUNK;
    if (n <= 0) return;

    for (int i = t; i < NB; i += 256) bcnt[i] = 0;
    __syncthreads();

    for (int i = t; i < n; i += 256) {
        int r = rows[base + i];
        atomicAdd(&bcnt[r >> BSHIFT], 1);
    }
    __syncthreads();

    // exclusive scan of bcnt[0..NB) across 128 lanes (Hillis-Steele, inclusive then shift)
    if (t < 128) sc[t] = (t < NB) ? bcnt[t] : 0;
    __syncthreads();
    for (int off = 1; off < 128; off <<= 1) {
        int v = 0;
        if (t >= off && t < 128) v = sc[t - off];
        __syncthreads();
        if (t < 128) sc[t] += v;
        __syncthreads();
    }
    if (t < NB) {
        int ex = sc[t] - bcnt[t];
        bofs[t] = ex;
        bcur[t] = ex;
        gbase[t] = atomicAdd(&bfill[t], bcnt[t]);
    }
    __syncthreads();

    // place records bucket-contiguously into the LDS stage
    for (int i = t; i < n; i += 256) {
        int r = rows[base + i];
        int c = cols[base + i];
        u16 hv = __builtin_bit_cast(u16, (_Float16)vals[base + i]);
        u32 lo = (u32)c | ((u32)hv << 16);
        u64 rec = ((u64)(u32)r << 32) | (u64)lo;
        int s = atomicAdd(&bcur[r >> BSHIFT], 1);
        stage[s] = rec;
    }
    __syncthreads();

    // flush: consecutive stage items within a run -> consecutive tmp addrs (coalesced)
    for (int i = t; i < n; i += 256) {
        u64 rec = stage[i];
        int b = (int)(rec >> (32 + BSHIFT));
        tmp[(size_t)(gbase[b] + (i - bofs[b]))] = rec;
    }
}

// Pass 2: one block per bucket. All row_fill atomics and epack stores for this
// bucket come from one block -> one XCD L2; lines written back once.
__global__ __launch_bounds__(256) void bin2_k(const u64* __restrict__ tmp, const int* __restrict__ row_ptr,
                                              const int* __restrict__ bfill,
                                              int* __restrict__ row_fill, u32* __restrict__ epack) {
    int b = blockIdx.x;
    int beg = row_ptr[b << BSHIFT];
    int end = bfill[b];  // bucket base + actual count after bin1
    for (int i = beg + (int)threadIdx.x; i < end; i += 256) {
        u64 rec = tmp[(size_t)i];
        int r = (int)(rec >> 32);
        int p = atomicAdd(&row_fill[r], 1);
        epack[p] = (u32)rec;
    }
}

// x0[v][b*64+f] = bf16(inputs[b,v,f]); thread per uint pair
__global__ void build_x0_k(const float* __restrict__ in, u32* __restrict__ x0u) {
    int i = blockIdx.x * blockDim.x + threadIdx.x;  // uint index: v*64 + p
    if (i < NV * 64) {
        int v = i >> 6, p = i & 63;
        int b = p >> 5;
        int f = (p & 31) * 2;
        const float* src = in + (size_t)b * (NV * 64) + (size_t)v * 64 + f;
        float2 t = *(const float2*)src;
        x0u[i] = pack_bf2(t.x, t.y);
    }
}

// Pre-permute weight to bf16 image: wimg[o*264 + c'] = bf16(Wflat[c*64+o]),
// c' = (c&3)*64 + (c>>2). Columns 256..263 are pad (never read).
__global__ void prep_w_k(const float* __restrict__ weight, u16* __restrict__ wimg) {
    int i = blockIdx.x * blockDim.x + threadIdx.x;
    if (i < 256 * 64) {
        int c = i >> 6, o = i & 63;
        int cp = ((c & 3) << 6) | (c >> 2);
        wimg[o * 264 + cp] = __builtin_bit_cast(u16, (__bf16)weight[i]);
    }
}

// One wave per row, quad-gather, tail-free (rows padded to 16-edge multiples).
// mode 0: L x ; 1: 2 L x - xprev
__global__ __launch_bounds__(256) void spmm_k(const u32* __restrict__ x,
                                              const u32* __restrict__ xprev,
                                              const int* __restrict__ row_ptr,
                                              const u32* __restrict__ epack,
                                              u32* __restrict__ xout, int mode) {
    int wave = (int)((blockIdx.x * blockDim.x + threadIdx.x) >> 6);
    u32 lane = threadIdx.x & 63;
    int row = __builtin_amdgcn_readfirstlane(wave);
    if (row >= NV) return;
    int beg = row_ptr[row];
    int end = row_ptr[row + 1];
    int q = (int)(lane >> 4);
    u32 g16 = lane & 15;

    float ax[4] = {0.f, 0.f, 0.f, 0.f};
    float ay[4] = {0.f, 0.f, 0.f, 0.f};

    for (int e = beg; e < end; e += 16) {
        u32 rec[4];
        uint4 gv[4];
        #pragma unroll
        for (int u = 0; u < 4; ++u) {
            rec[u] = epack[e + 4 * u + q];
            gv[u] = *(const uint4*)(x + ((rec[u] & 0xffffu) << 6) + (g16 << 2));
        }
        #pragma unroll
        for (int u = 0; u < 4; ++u) {
            float w = unpack_f16hi(rec[u]);
            ax[0] += w * bflo(gv[u].x); ay[0] += w * bfhi(gv[u].x);
            ax[1] += w * bflo(gv[u].y); ay[1] += w * bfhi(gv[u].y);
            ax[2] += w * bflo(gv[u].z); ay[2] += w * bfhi(gv[u].z);
            ax[3] += w * bflo(gv[u].w); ay[3] += w * bfhi(gv[u].w);
        }
    }

    #pragma unroll
    for (int m = 16; m <= 32; m <<= 1) {
        #pragma unroll
        for (int j = 0; j < 4; ++j) {
            ax[j] += __shfl_xor(ax[j], m, 64);
            ay[j] += __shfl_xor(ay[j], m, 64);
        }
    }

    if (q == 0) {
        if (mode) {
            uint4 pv = *(const uint4*)(xprev + ((u32)row << 6) + (g16 << 2));
            ax[0] = 2.f * ax[0] - bflo(pv.x); ay[0] = 2.f * ay[0] - bfhi(pv.x);
            ax[1] = 2.f * ax[1] - bflo(pv.y); ay[1] = 2.f * ay[1] - bfhi(pv.y);
            ax[2] = 2.f * ax[2] - bflo(pv.z); ay[2] = 2.f * ay[2] - bfhi(pv.z);
            ax[3] = 2.f * ax[3] - bflo(pv.w); ay[3] = 2.f * ay[3] - bfhi(pv.w);
        }
        uint4 o;
        o.x = pack_bf2(ax[0], ay[0]);
        o.y = pack_bf2(ax[1], ay[1]);
        o.z = pack_bf2(ax[2], ay[2]);
        o.w = pack_bf2(ax[3], ay[3]);
        *(uint4*)(xout + ((u32)row << 6) + (g16 << 2)) = o;
    }
}

// MFMA epilogue: C[100000 x 64] = X[100000 x 256] @ W'[256 x 64] + bias.
// 2 tiles per wave (shared B-frags), 8 tiles per block. W from prebuilt bf16 image.
__global__ __launch_bounds__(256) void final_k(const u16* __restrict__ x_all,
                                               const u16* __restrict__ wimg,
                                               const float* __restrict__ bias,
                                               float* __restrict__ out) {
    __shared__ u16 Wt[64 * 264];
    {
        const u32* src = (const u32*)wimg;
        u32* dst = (u32*)Wt;
        #pragma unroll 4
        for (int i = threadIdx.x; i < 64 * 264 / 2; i += 256) dst[i] = src[i];
    }
    __syncthreads();

    int lane = threadIdx.x & 63;
    int wid = threadIdx.x >> 6;
    int pair = blockIdx.x * 4 + wid;   // tiles 2*pair, 2*pair+1
    int t0 = pair * 2;
    if (t0 >= NTILES) return;

    int m = lane & 15;
    int q8 = (lane >> 4) * 8;

    int r0 = t0 * 16 + m;        // row = v*2+b, tile t0
    int r1 = r0 + 16;            // tile t0+1
    const u16* arow0 = x_all + (size_t)(r0 >> 1) * XROW + (r0 & 1) * 64;
    const u16* arow1 = x_all + (size_t)(r1 >> 1) * XROW + (r1 & 1) * 64;

    f32x4 accA[4] = {{0,0,0,0},{0,0,0,0},{0,0,0,0},{0,0,0,0}};
    f32x4 accB[4] = {{0,0,0,0},{0,0,0,0},{0,0,0,0},{0,0,0,0}};

    #pragma unroll
    for (int kb = 0; kb < 8; ++kb) {
        int cb = kb * 32 + q8;
        int arr = cb >> 6;
        int f0 = cb & 63;
        size_t aoff = (size_t)arr * (NV * XROW) + f0;
        bf16x8 a0 = *(const bf16x8*)(arow0 + aoff);
        bf16x8 a1 = *(const bf16x8*)(arow1 + aoff);
        #pragma unroll
        for (int j = 0; j < 4; ++j) {
            bf16x8 bj = *(const bf16x8*)&Wt[(j * 16 + m) * 264 + kb * 32 + q8];
            accA[j] = __builtin_amdgcn_mfma_f32_16x16x32_bf16(a0, bj, accA[j], 0, 0, 0);
            accB[j] = __builtin_amdgcn_mfma_f32_16x16x32_bf16(a1, bj, accB[j], 0, 0, 0);
        }
    }

    float bv[4];
    #pragma unroll
    for (int j = 0; j < 4; ++j) bv[j] = bias[j * 16 + m];

    #pragma unroll
    for (int half = 0; half < 2; ++half) {
        int rbase = (t0 + half) * 16 + (lane >> 4) * 4;
        f32x4* acc = half ? accB : accA;
        #pragma unroll
        for (int reg = 0; reg < 4; ++reg) {
            int rr = rbase + reg;
            float* op = out + (size_t)(rr & 1) * (NV * 64) + (size_t)(rr >> 1) * 64;
            #pragma unroll
            for (int j = 0; j < 4; ++j) op[j * 16 + m] = acc[j][reg] + bv[j];
        }
    }
}

extern "C" void kernel_launch(void* const* d_in, const int* in_sizes, int n_in,
                              void* d_out, int out_size, void* d_ws, size_t ws_size,
                              hipStream_t stream) {
    const float* inputs = (const float*)d_in[0];
    const float* weight = (const float*)d_in[1];
    const float* bias   = (const float*)d_in[2];
    const float* lapv   = (const float*)d_in[3];
    const int*   lrows  = (const int*)d_in[4];
    const int*   lcols  = (const int*)d_in[5];
    float* out = (float*)d_out;

    char* ws = (char*)d_ws;
    size_t o = 0;
    auto alloc = [&](size_t bytes) -> void* {
        void* p = ws + o;
        o += (bytes + 255) & ~(size_t)255;
        return p;
    };
    u16* x_all = (u16*)alloc((size_t)4 * NV * XROW * 2);  // x0..x3 contiguous, bf16
    u32* epack = (u32*)alloc((size_t)EPMAX * 4);
    u64* tmp   = (u64*)alloc((size_t)EPMAX * 8);          // bucketed u64 recs
    int* row_ptr = (int*)alloc((size_t)(NV + 1) * 4);
    int* row_fill = (int*)alloc((size_t)(NV + 1) * 4);
    int* cnt = (int*)alloc((size_t)NV * 4);
    int* bsum = (int*)alloc((size_t)SCAN_NBLK * 4);
    int* bfill = (int*)alloc((size_t)NB * 4);
    u16* wimg = (u16*)alloc((size_t)64 * 264 * 2);
    (void)ws_size; (void)in_sizes; (void)n_in; (void)out_size;

    u32* x0 = (u32*)(x_all + (size_t)0 * NV * XROW);
    u32* x1 = (u32*)(x_all + (size_t)1 * NV * XROW);
    u32* x2 = (u32*)(x_all + (size_t)2 * NV * XROW);
    u32* x3 = (u32*)(x_all + (size_t)3 * NV * XROW);

    hipMemsetAsync(cnt, 0, (size_t)NV * 4, stream);
    hipMemsetAsync(epack, 0, (size_t)EPMAX * 4, stream);
    hist_k<<<(NE + 255) / 256, 256, 0, stream>>>(lrows, cnt);
    scan1_k<<<SCAN_NBLK, 256, 0, stream>>>(cnt, bsum);
    scan2_k<<<1, 256, 0, stream>>>(bsum);
    scan3_k<<<SCAN_NBLK, 256, 0, stream>>>(cnt, bsum, row_ptr, row_fill, bfill);
    bin1_k<<<P1_BLOCKS, 256, 0, stream>>>(lrows, lcols, lapv, bfill, tmp);
    bin2_k<<<NB, 256, 0, stream>>>(tmp, row_ptr, bfill, row_fill, epack);
    build_x0_k<<<(NV * 64 + 255) / 256, 256, 0, stream>>>(inputs, x0);
    prep_w_k<<<64, 256, 0, stream>>>(weight, wimg);

    spmm_k<<<(NV + 3) / 4, 256, 0, stream>>>(x0, nullptr, row_ptr, epack, x1, 0);
    spmm_k<<<(NV + 3) / 4, 256, 0, stream>>>(x1, x0, row_ptr, epack, x2, 1);
    spmm_k<<<(NV + 3) / 4, 256, 0, stream>>>(x2, x1, row_ptr, epack, x3, 1);

    final_k<<<(NTILES / 2 + 3) / 4, 256, 0, stream>>>(x_all, wimg, bias, out);
}

// Round 2
// 230.890 us; speedup vs baseline: 1.2430x; 1.2289x over previous
//
#include <hip/hip_runtime.h>
#include <hip/hip_bf16.h>

// ChebConv K=4. out[b,v,o] = bias[o] + sum_{c<256} xs[c&3][v,(c>>2)*2+b] * Wflat[c*64+o]
// R12: fully bucket-local CSR build, zero global atomics.
//   - hist_k + scan1/2/3 + bin2_k DELETED.
//   - bin1_k: bucket edges by row>>7 into fixed-capacity (CAP=3072) slices of tmp
//     (391 buckets of 128 rows; counts are Binomial(800K,128/50K) mean 2048
//     sigma 45 -> CAP is +22 sigma, deterministically safe). LDS-staged
//     coalesced flush. Only cross-block sync: 1 atomicAdd per bucket per block
//     on binctr.
//   - bcnt_k: per bucket, LDS row histogram -> rowc[] + padded bucket total.
//   - scanb_k: 391-element scan -> bucket bases in epack, row_ptr[NV].
//   - place_k: per bucket, LDS scan of padded row counts -> row_ptr, then place
//     records with LDS fill counters (fast) into an L2-local epack window.
// spmm / final_k unchanged.

#define NV 50000
#define NE 800000
#define XROW 128       // elements per x row = 2 batches * 64 features
#define NROWS 100000
#define NTILES 6250    // NROWS / 16
#define EPMAX 1600000  // >= NE + 15*NV (padded CSR upper bound)
#define BSHIFT 7
#define RPB 128        // rows per bucket
#define NB 391         // ceil(NV / RPB)
#define CAP 3072       // per-bucket tmp capacity (mean 2048, +22 sigma)
#define CHUNK 4096     // edges per bin1 block
#define P1_BLOCKS 196  // ceil(NE / CHUNK)

using u16 = unsigned short;
using u32 = unsigned int;
using u64 = unsigned long long;
typedef __bf16 bf16x8 __attribute__((ext_vector_type(8)));
typedef float f32x4 __attribute__((ext_vector_type(4)));

__device__ __forceinline__ float bflo(u32 g) { return __uint_as_float(g << 16); }
__device__ __forceinline__ float bfhi(u32 g) { return __uint_as_float(g & 0xffff0000u); }
__device__ __forceinline__ u32 pack_bf2(float a, float b) {
    u16 ha = __builtin_bit_cast(u16, (__bf16)a);
    u16 hb = __builtin_bit_cast(u16, (__bf16)b);
    return (u32)ha | ((u32)hb << 16);
}
__device__ __forceinline__ float unpack_f16hi(u32 rec) {
    u16 h = (u16)(rec >> 16);
    return (float)__builtin_bit_cast(_Float16, h);
}
__device__ __forceinline__ int pad16(int n) { return (n + 15) & ~15; }

// Pass 1: bin edges by row>>BSHIFT into fixed-capacity bucket slices of tmp.
// rec = row<<32 | col | f16(val)<<16. LDS-staged so each bucket run flushes
// as a contiguous coalesced burst.
__global__ __launch_bounds__(256) void bin1_k(const int* __restrict__ rows, const int* __restrict__ cols,
                                              const float* __restrict__ vals,
                                              int* __restrict__ binctr, u64* __restrict__ tmp) {
    __shared__ int bcnt[NB];
    __shared__ int bofs[NB];
    __shared__ int bcur[NB];
    __shared__ int gbase[NB];
    __shared__ int ps[256];
    __shared__ u64 stage[CHUNK];  // 32 KB
    int t = threadIdx.x;
    int base = blockIdx.x * CHUNK;
    int n = NE - base;
    if (n > CHUNK) n = CHUNK;
    if (n <= 0) return;

    for (int i = t; i < NB; i += 256) bcnt[i] = 0;
    __syncthreads();

    for (int i = t; i < n; i += 256) {
        atomicAdd(&bcnt[rows[base + i] >> BSHIFT], 1);
    }
    __syncthreads();

    // exclusive scan over NB<=512 buckets: 2 slots per thread + 256-scan of pair sums
    int i0 = 2 * t, i1 = 2 * t + 1;
    int a0 = (i0 < NB) ? bcnt[i0] : 0;
    int a1 = (i1 < NB) ? bcnt[i1] : 0;
    ps[t] = a0 + a1;
    __syncthreads();
    for (int off = 1; off < 256; off <<= 1) {
        int v = (t >= off) ? ps[t - off] : 0;
        __syncthreads();
        ps[t] += v;
        __syncthreads();
    }
    int eb = ps[t] - (a0 + a1);
    if (i0 < NB) { bofs[i0] = eb;      bcur[i0] = eb;      gbase[i0] = i0 * CAP + atomicAdd(&binctr[i0], a0); }
    if (i1 < NB) { bofs[i1] = eb + a0; bcur[i1] = eb + a0; gbase[i1] = i1 * CAP + atomicAdd(&binctr[i1], a1); }
    __syncthreads();

    // place records bucket-contiguously into the LDS stage
    for (int i = t; i < n; i += 256) {
        int r = rows[base + i];
        int c = cols[base + i];
        u16 hv = __builtin_bit_cast(u16, (_Float16)vals[base + i]);
        u64 rec = ((u64)(u32)r << 32) | (u64)((u32)c | ((u32)hv << 16));
        int s = atomicAdd(&bcur[r >> BSHIFT], 1);
        stage[s] = rec;
    }
    __syncthreads();

    // flush: consecutive stage items within a run -> consecutive tmp addrs (coalesced)
    for (int i = t; i < n; i += 256) {
        u64 rec = stage[i];
        int b = (int)(rec >> (32 + BSHIFT));
        tmp[(size_t)(gbase[b] + (i - bofs[b]))] = rec;
    }
}

// Pass 2a: per-bucket row histogram (LDS) -> rowc[] and padded bucket total.
__global__ __launch_bounds__(256) void bcnt_k(const u64* __restrict__ tmp, const int* __restrict__ binctr,
                                              int* __restrict__ rowc, int* __restrict__ btot) {
    __shared__ int rc[RPB];
    __shared__ int rs[RPB];
    int b = blockIdx.x, t = threadIdx.x;
    int n = binctr[b];
    const u64* rec = tmp + (size_t)b * CAP;
    if (t < RPB) rc[t] = 0;
    __syncthreads();
    for (int i = t; i < n; i += 256) {
        atomicAdd(&rc[(int)(rec[i] >> 32) & (RPB - 1)], 1);
    }
    __syncthreads();
    if (t < RPB) {
        rowc[b * RPB + t] = rc[t];
        rs[t] = pad16(rc[t]);
    }
    __syncthreads();
    for (int off = 64; off > 0; off >>= 1) {
        if (t < off) rs[t] += rs[t + off];
        __syncthreads();
    }
    if (t == 0) btot[b] = rs[0];
}

// Pass 2b: exclusive scan of padded bucket totals -> bucket bases; total -> row_ptr[NV].
__global__ __launch_bounds__(256) void scanb_k(const int* __restrict__ btot, int* __restrict__ bbase,
                                               int* __restrict__ row_ptr) {
    __shared__ int ps[256];
    int t = threadIdx.x;
    int i0 = 2 * t, i1 = 2 * t + 1;
    int a0 = (i0 < NB) ? btot[i0] : 0;
    int a1 = (i1 < NB) ? btot[i1] : 0;
    ps[t] = a0 + a1;
    __syncthreads();
    for (int off = 1; off < 256; off <<= 1) {
        int v = (t >= off) ? ps[t - off] : 0;
        __syncthreads();
        ps[t] += v;
        __syncthreads();
    }
    int eb = ps[t] - (a0 + a1);
    if (i0 < NB) bbase[i0] = eb;
    if (i1 < NB) bbase[i1] = eb + a0;
    if (t == 255) row_ptr[NV] = ps[255];
}

// Pass 2c: per bucket: LDS scan of padded row counts -> row_ptr; place records
// via LDS fill counters into the bucket's L2-local epack window.
__global__ __launch_bounds__(256) void place_k(const u64* __restrict__ tmp, const int* __restrict__ binctr,
                                               const int* __restrict__ rowc, const int* __restrict__ bbase,
                                               int* __restrict__ row_ptr, u32* __restrict__ epack) {
    __shared__ int rc[RPB];   // fill counters
    __shared__ int ro[RPB];   // row base offsets (exclusive scan of padded counts)
    int b = blockIdx.x, t = threadIdx.x;
    int n = binctr[b];
    int base = bbase[b];
    const u64* rec = tmp + (size_t)b * CAP;

    int cv = (t < RPB) ? rowc[b * RPB + t] : 0;
    int pv = pad16(cv);
    if (t < RPB) ro[t] = pv;
    __syncthreads();
    for (int off = 1; off < RPB; off <<= 1) {
        int v = 0;
        if (t < RPB && t >= off) v = ro[t - off];
        __syncthreads();
        if (t < RPB) ro[t] += v;
        __syncthreads();
    }
    if (t < RPB) {
        int ex = ro[t] - pv;   // exclusive
        ro[t] = ex;
        rc[t] = 0;
        int v = (b << BSHIFT) + t;
        if (v < NV) row_ptr[v] = base + ex;
    }
    __syncthreads();
    for (int i = t; i < n; i += 256) {
        u64 r64 = rec[i];
        int r = (int)(r64 >> 32) & (RPB - 1);
        int p = base + ro[r] + atomicAdd(&rc[r], 1);
        epack[p] = (u32)r64;
    }
}

// x0[v][b*64+f] = bf16(inputs[b,v,f]); thread per uint pair
__global__ void build_x0_k(const float* __restrict__ in, u32* __restrict__ x0u) {
    int i = blockIdx.x * blockDim.x + threadIdx.x;  // uint index: v*64 + p
    if (i < NV * 64) {
        int v = i >> 6, p = i & 63;
        int b = p >> 5;
        int f = (p & 31) * 2;
        const float* src = in + (size_t)b * (NV * 64) + (size_t)v * 64 + f;
        float2 t = *(const float2*)src;
        x0u[i] = pack_bf2(t.x, t.y);
    }
}

// Pre-permute weight to bf16 image: wimg[o*264 + c'] = bf16(Wflat[c*64+o]),
// c' = (c&3)*64 + (c>>2). Columns 256..263 are pad (never read).
__global__ void prep_w_k(const float* __restrict__ weight, u16* __restrict__ wimg) {
    int i = blockIdx.x * blockDim.x + threadIdx.x;
    if (i < 256 * 64) {
        int c = i >> 6, o = i & 63;
        int cp = ((c & 3) << 6) | (c >> 2);
        wimg[o * 264 + cp] = __builtin_bit_cast(u16, (__bf16)weight[i]);
    }
}

// One wave per row, quad-gather, tail-free (rows padded to 16-edge multiples).
// mode 0: L x ; 1: 2 L x - xprev
__global__ __launch_bounds__(256) void spmm_k(const u32* __restrict__ x,
                                              const u32* __restrict__ xprev,
                                              const int* __restrict__ row_ptr,
                                              const u32* __restrict__ epack,
                                              u32* __restrict__ xout, int mode) {
    int wave = (int)((blockIdx.x * blockDim.x + threadIdx.x) >> 6);
    u32 lane = threadIdx.x & 63;
    int row = __builtin_amdgcn_readfirstlane(wave);
    if (row >= NV) return;
    int beg = row_ptr[row];
    int end = row_ptr[row + 1];
    int q = (int)(lane >> 4);
    u32 g16 = lane & 15;

    float ax[4] = {0.f, 0.f, 0.f, 0.f};
    float ay[4] = {0.f, 0.f, 0.f, 0.f};

    for (int e = beg; e < end; e += 16) {
        u32 rec[4];
        uint4 gv[4];
        #pragma unroll
        for (int u = 0; u < 4; ++u) {
            rec[u] = epack[e + 4 * u + q];
            gv[u] = *(const uint4*)(x + ((rec[u] & 0xffffu) << 6) + (g16 << 2));
        }
        #pragma unroll
        for (int u = 0; u < 4; ++u) {
            float w = unpack_f16hi(rec[u]);
            ax[0] += w * bflo(gv[u].x); ay[0] += w * bfhi(gv[u].x);
            ax[1] += w * bflo(gv[u].y); ay[1] += w * bfhi(gv[u].y);
            ax[2] += w * bflo(gv[u].z); ay[2] += w * bfhi(gv[u].z);
            ax[3] += w * bflo(gv[u].w); ay[3] += w * bfhi(gv[u].w);
        }
    }

    #pragma unroll
    for (int m = 16; m <= 32; m <<= 1) {
        #pragma unroll
        for (int j = 0; j < 4; ++j) {
            ax[j] += __shfl_xor(ax[j], m, 64);
            ay[j] += __shfl_xor(ay[j], m, 64);
        }
    }

    if (q == 0) {
        if (mode) {
            uint4 pv = *(const uint4*)(xprev + ((u32)row << 6) + (g16 << 2));
            ax[0] = 2.f * ax[0] - bflo(pv.x); ay[0] = 2.f * ay[0] - bfhi(pv.x);
            ax[1] = 2.f * ax[1] - bflo(pv.y); ay[1] = 2.f * ay[1] - bfhi(pv.y);
            ax[2] = 2.f * ax[2] - bflo(pv.z); ay[2] = 2.f * ay[2] - bfhi(pv.z);
            ax[3] = 2.f * ax[3] - bflo(pv.w); ay[3] = 2.f * ay[3] - bfhi(pv.w);
        }
        uint4 o;
        o.x = pack_bf2(ax[0], ay[0]);
        o.y = pack_bf2(ax[1], ay[1]);
        o.z = pack_bf2(ax[2], ay[2]);
        o.w = pack_bf2(ax[3], ay[3]);
        *(uint4*)(xout + ((u32)row << 6) + (g16 << 2)) = o;
    }
}

// MFMA epilogue: C[100000 x 64] = X[100000 x 256] @ W'[256 x 64] + bias.
// 2 tiles per wave (shared B-frags), 8 tiles per block. W from prebuilt bf16 image.
__global__ __launch_bounds__(256) void final_k(const u16* __restrict__ x_all,
                                               const u16* __restrict__ wimg,
                                               const float* __restrict__ bias,
                                               float* __restrict__ out) {
    __shared__ u16 Wt[64 * 264];
    {
        const u32* src = (const u32*)wimg;
        u32* dst = (u32*)Wt;
        #pragma unroll 4
        for (int i = threadIdx.x; i < 64 * 264 / 2; i += 256) dst[i] = src[i];
    }
    __syncthreads();

    int lane = threadIdx.x & 63;
    int wid = threadIdx.x >> 6;
    int pair = blockIdx.x * 4 + wid;   // tiles 2*pair, 2*pair+1
    int t0 = pair * 2;
    if (t0 >= NTILES) return;

    int m = lane & 15;
    int q8 = (lane >> 4) * 8;

    int r0 = t0 * 16 + m;        // row = v*2+b, tile t0
    int r1 = r0 + 16;            // tile t0+1
    const u16* arow0 = x_all + (size_t)(r0 >> 1) * XROW + (r0 & 1) * 64;
    const u16* arow1 = x_all + (size_t)(r1 >> 1) * XROW + (r1 & 1) * 64;

    f32x4 accA[4] = {{0,0,0,0},{0,0,0,0},{0,0,0,0},{0,0,0,0}};
    f32x4 accB[4] = {{0,0,0,0},{0,0,0,0},{0,0,0,0},{0,0,0,0}};

    #pragma unroll
    for (int kb = 0; kb < 8; ++kb) {
        int cb = kb * 32 + q8;
        int arr = cb >> 6;
        int f0 = cb & 63;
        size_t aoff = (size_t)arr * (NV * XROW) + f0;
        bf16x8 a0 = *(const bf16x8*)(arow0 + aoff);
        bf16x8 a1 = *(const bf16x8*)(arow1 + aoff);
        #pragma unroll
        for (int j = 0; j < 4; ++j) {
            bf16x8 bj = *(const bf16x8*)&Wt[(j * 16 + m) * 264 + kb * 32 + q8];
            accA[j] = __builtin_amdgcn_mfma_f32_16x16x32_bf16(a0, bj, accA[j], 0, 0, 0);
            accB[j] = __builtin_amdgcn_mfma_f32_16x16x32_bf16(a1, bj, accB[j], 0, 0, 0);
        }
    }

    float bv[4];
    #pragma unroll
    for (int j = 0; j < 4; ++j) bv[j] = bias[j * 16 + m];

    #pragma unroll
    for (int half = 0; half < 2; ++half) {
        int rbase = (t0 + half) * 16 + (lane >> 4) * 4;
        f32x4* acc = half ? accB : accA;
        #pragma unroll
        for (int reg = 0; reg < 4; ++reg) {
            int rr = rbase + reg;
            float* op = out + (size_t)(rr & 1) * (NV * 64) + (size_t)(rr >> 1) * 64;
            #pragma unroll
            for (int j = 0; j < 4; ++j) op[j * 16 + m] = acc[j][reg] + bv[j];
        }
    }
}

extern "C" void kernel_launch(void* const* d_in, const int* in_sizes, int n_in,
                              void* d_out, int out_size, void* d_ws, size_t ws_size,
                              hipStream_t stream) {
    const float* inputs = (const float*)d_in[0];
    const float* weight = (const float*)d_in[1];
    const float* bias   = (const float*)d_in[2];
    const float* lapv   = (const float*)d_in[3];
    const int*   lrows  = (const int*)d_in[4];
    const int*   lcols  = (const int*)d_in[5];
    float* out = (float*)d_out;

    char* ws = (char*)d_ws;
    size_t o = 0;
    auto alloc = [&](size_t bytes) -> void* {
        void* p = ws + o;
        o += (bytes + 255) & ~(size_t)255;
        return p;
    };
    u16* x_all = (u16*)alloc((size_t)4 * NV * XROW * 2);  // x0..x3 contiguous, bf16
    u32* epack = (u32*)alloc((size_t)EPMAX * 4);
    u64* tmp   = (u64*)alloc((size_t)NB * CAP * 8);       // fixed-capacity bucket slices
    int* row_ptr = (int*)alloc((size_t)(NV + 1) * 4);
    int* binctr  = (int*)alloc((size_t)NB * 4);
    int* btot    = (int*)alloc((size_t)NB * 4);
    int* bbase   = (int*)alloc((size_t)NB * 4);
    int* rowc    = (int*)alloc((size_t)NB * RPB * 4);
    u16* wimg = (u16*)alloc((size_t)64 * 264 * 2);
    (void)ws_size; (void)in_sizes; (void)n_in; (void)out_size;

    u32* x0 = (u32*)(x_all + (size_t)0 * NV * XROW);
    u32* x1 = (u32*)(x_all + (size_t)1 * NV * XROW);
    u32* x2 = (u32*)(x_all + (size_t)2 * NV * XROW);
    u32* x3 = (u32*)(x_all + (size_t)3 * NV * XROW);

    hipMemsetAsync(binctr, 0, (size_t)NB * 4, stream);
    hipMemsetAsync(epack, 0, (size_t)EPMAX * 4, stream);
    bin1_k<<<P1_BLOCKS, 256, 0, stream>>>(lrows, lcols, lapv, binctr, tmp);
    bcnt_k<<<NB, 256, 0, stream>>>(tmp, binctr, rowc, btot);
    scanb_k<<<1, 256, 0, stream>>>(btot, bbase, row_ptr);
    place_k<<<NB, 256, 0, stream>>>(tmp, binctr, rowc, bbase, row_ptr, epack);
    build_x0_k<<<(NV * 64 + 255) / 256, 256, 0, stream>>>(inputs, x0);
    prep_w_k<<<64, 256, 0, stream>>>(weight, wimg);

    spmm_k<<<(NV + 3) / 4, 256, 0, stream>>>(x0, nullptr, row_ptr, epack, x1, 0);
    spmm_k<<<(NV + 3) / 4, 256, 0, stream>>>(x1, x0, row_ptr, epack, x2, 1);
    spmm_k<<<(NV + 3) / 4, 256, 0, stream>>>(x2, x1, row_ptr, epack, x3, 1);

    final_k<<<(NTILES / 2 + 3) / 4, 256, 0, stream>>>(x_all, wimg, bias, out);
}